// Round 2
// baseline (826.583 us; speedup 1.0000x reference)
//
#include <hip/hip_runtime.h>

#define NPTS 2000000
#define WDIM 160
#define CH 12
// points per block
#define BLK 256

typedef float v4f __attribute__((ext_vector_type(4)));

__device__ __forceinline__ void fma4(v4f& a, float w, const v4f& v) {
    a.x = fmaf(w, v.x, a.x);
    a.y = fmaf(w, v.y, a.y);
    a.z = fmaf(w, v.z, a.z);
    a.w = fmaf(w, v.w, a.w);
}

__global__ __launch_bounds__(BLK) void trilerp_kernel(
    const float* __restrict__ xyz,
    const float* __restrict__ grid,
    float* __restrict__ out,
    int n)
{
    __shared__ float sxyz[BLK * 3];

    const int tid = threadIdx.x;
    const int blockStart = blockIdx.x * BLK;

    // coalesced stage of this block's xyz into LDS
    const int base = blockStart * 3;
    const int total = n * 3;
    #pragma unroll
    for (int k = tid; k < BLK * 3; k += BLK) {
        int g = base + k;
        sxyz[k] = (g < total) ? xyz[g] : 0.0f;
    }
    __syncthreads();

    const int i = blockStart + tid;
    if (i >= n) return;

    float px = sxyz[tid * 3 + 0] * 159.0f;
    float py = sxyz[tid * 3 + 1] * 159.0f;
    float pz = sxyz[tid * 3 + 2] * 159.0f;

    px = fminf(fmaxf(px, 0.0f), 159.0f);
    py = fminf(fmaxf(py, 0.0f), 159.0f);
    pz = fminf(fmaxf(pz, 0.0f), 159.0f);

    // px >= 0 so truncation == floor
    int x0 = (int)px, y0 = (int)py, z0 = (int)pz;
    float fx = px - (float)x0;
    float fy = py - (float)y0;
    float fz = pz - (float)z0;
    int x1 = min(x0 + 1, WDIM - 1);
    int y1 = min(y0 + 1, WDIM - 1);
    int z1 = min(z0 + 1, WDIM - 1);

    float gx = 1.0f - fx, gy = 1.0f - fy, gz = 1.0f - fz;

    // weights
    const float w000 = gx * gy * gz;
    const float w001 = gx * gy * fz;
    const float w010 = gx * fy * gz;
    const float w011 = gx * fy * fz;
    const float w100 = fx * gy * gz;
    const float w101 = fx * gy * fz;
    const float w110 = fx * fy * gz;
    const float w111 = fx * fy * fz;

    // row bases (in floats). voxel = 12 floats = 48 B, 16B-aligned.
    const int b00 = ((x0 * WDIM + y0) * WDIM) * CH;
    const int b01 = ((x0 * WDIM + y1) * WDIM) * CH;
    const int b10 = ((x1 * WDIM + y0) * WDIM) * CH;
    const int b11 = ((x1 * WDIM + y1) * WDIM) * CH;
    const int oz0 = z0 * CH;
    const int oz1 = z1 * CH;

    v4f a0 = (v4f)(0.0f);
    v4f a1 = (v4f)(0.0f);
    v4f a2 = (v4f)(0.0f);

    const v4f* c;

    c = reinterpret_cast<const v4f*>(grid + b00 + oz0);
    fma4(a0, w000, c[0]); fma4(a1, w000, c[1]); fma4(a2, w000, c[2]);
    c = reinterpret_cast<const v4f*>(grid + b00 + oz1);
    fma4(a0, w001, c[0]); fma4(a1, w001, c[1]); fma4(a2, w001, c[2]);
    c = reinterpret_cast<const v4f*>(grid + b01 + oz0);
    fma4(a0, w010, c[0]); fma4(a1, w010, c[1]); fma4(a2, w010, c[2]);
    c = reinterpret_cast<const v4f*>(grid + b01 + oz1);
    fma4(a0, w011, c[0]); fma4(a1, w011, c[1]); fma4(a2, w011, c[2]);
    c = reinterpret_cast<const v4f*>(grid + b10 + oz0);
    fma4(a0, w100, c[0]); fma4(a1, w100, c[1]); fma4(a2, w100, c[2]);
    c = reinterpret_cast<const v4f*>(grid + b10 + oz1);
    fma4(a0, w101, c[0]); fma4(a1, w101, c[1]); fma4(a2, w101, c[2]);
    c = reinterpret_cast<const v4f*>(grid + b11 + oz0);
    fma4(a0, w110, c[0]); fma4(a1, w110, c[1]); fma4(a2, w110, c[2]);
    c = reinterpret_cast<const v4f*>(grid + b11 + oz1);
    fma4(a0, w111, c[0]); fma4(a1, w111, c[1]); fma4(a2, w111, c[2]);

    // contiguous 48 B per thread, 16B-aligned; nontemporal to keep grid in L2/L3
    v4f* o = reinterpret_cast<v4f*>(out + (size_t)i * CH);
    __builtin_nontemporal_store(a0, o + 0);
    __builtin_nontemporal_store(a1, o + 1);
    __builtin_nontemporal_store(a2, o + 2);
}

extern "C" void kernel_launch(void* const* d_in, const int* in_sizes, int n_in,
                              void* d_out, int out_size, void* d_ws, size_t ws_size,
                              hipStream_t stream) {
    const float* xyz  = (const float*)d_in[0];
    const float* grid = (const float*)d_in[1];
    float* out = (float*)d_out;
    const int n = in_sizes[0] / 3;  // 2,000,000 points

    const int blocks = (n + BLK - 1) / BLK;
    trilerp_kernel<<<blocks, BLK, 0, stream>>>(xyz, grid, out, n);
}

// Round 3
// 689.794 us; speedup vs baseline: 1.1983x; 1.1983x over previous
//
#include <hip/hip_runtime.h>

#define WDIM 160
#define CH 12
#define BLK 256

// binning params
#define CELL 10
#define NB 16                    // cells per dim
#define NBUCKETS (NB*NB*NB)      // 4096
#define SUB 11                   // subgrid voxels per dim (cell + 1 halo)
#define SUBV (SUB*SUB*SUB)       // 1331 voxels
#define SUBQ (SUBV*3)            // 3993 float4s = 63888 B LDS

typedef float v4f __attribute__((ext_vector_type(4)));

__device__ __forceinline__ void fma4(v4f& a, float w, const v4f& v) {
    a.x = fmaf(w, v.x, a.x);
    a.y = fmaf(w, v.y, a.y);
    a.z = fmaf(w, v.z, a.z);
    a.w = fmaf(w, v.w, a.w);
}

__device__ __forceinline__ void point_prep(const float* xyz, int i,
                                           float& px, float& py, float& pz,
                                           int& x0, int& y0, int& z0, int& bucket) {
    px = fminf(fmaxf(xyz[3*i+0] * 159.0f, 0.0f), 159.0f);
    py = fminf(fmaxf(xyz[3*i+1] * 159.0f, 0.0f), 159.0f);
    pz = fminf(fmaxf(xyz[3*i+2] * 159.0f, 0.0f), 159.0f);
    x0 = (int)px; y0 = (int)py; z0 = (int)pz;            // px>=0: trunc == floor
    bucket = ((x0/CELL)*NB + (y0/CELL))*NB + (z0/CELL);  // bucket from x0 => consistent
}

// ---- K1: histogram ----
__global__ __launch_bounds__(BLK) void hist_kernel(const float* __restrict__ xyz,
                                                   unsigned* __restrict__ hist, int n) {
    __shared__ unsigned lh[NBUCKETS];
    for (int k = threadIdx.x; k < NBUCKETS; k += BLK) lh[k] = 0;
    __syncthreads();
    const int stride = gridDim.x * BLK;
    for (int i = blockIdx.x * BLK + threadIdx.x; i < n; i += stride) {
        float px, py, pz; int x0, y0, z0, b;
        point_prep(xyz, i, px, py, pz, x0, y0, z0, b);
        atomicAdd(&lh[b], 1u);
    }
    __syncthreads();
    for (int k = threadIdx.x; k < NBUCKETS; k += BLK) {
        unsigned v = lh[k];
        if (v) atomicAdd(&hist[k], v);
    }
}

// ---- K2: exclusive scan of 4096 counts (single block) ----
__global__ __launch_bounds__(BLK) void scan_kernel(const unsigned* __restrict__ hist,
                                                   unsigned* __restrict__ starts,
                                                   unsigned* __restrict__ cursor) {
    __shared__ unsigned part[BLK];
    __shared__ unsigned base[BLK];
    const int t = threadIdx.x;
    unsigned h[16];
    unsigned s = 0;
    for (int j = 0; j < 16; j++) { h[j] = hist[t*16 + j]; s += h[j]; }
    part[t] = s;
    __syncthreads();
    if (t == 0) {
        unsigned run = 0;
        for (int k = 0; k < BLK; k++) { base[k] = run; run += part[k]; }
        starts[NBUCKETS] = run;   // == n
    }
    __syncthreads();
    unsigned run = base[t];
    for (int j = 0; j < 16; j++) {
        starts[t*16 + j] = run;
        cursor[t*16 + j] = run;
        run += h[j];
    }
}

// ---- K3: scatter records into bucket order ----
__global__ __launch_bounds__(BLK) void scatter_kernel(const float* __restrict__ xyz,
                                                      unsigned* __restrict__ cursor,
                                                      v4f* __restrict__ recs, int n) {
    const int stride = gridDim.x * BLK;
    for (int i = blockIdx.x * BLK + threadIdx.x; i < n; i += stride) {
        float px, py, pz; int x0, y0, z0, b;
        point_prep(xyz, i, px, py, pz, x0, y0, z0, b);
        unsigned pos = atomicAdd(&cursor[b], 1u);
        v4f r; r.x = px; r.y = py; r.z = pz; r.w = __uint_as_float((unsigned)i);
        recs[pos] = r;
    }
}

// ---- K4: per-bucket gather with LDS-staged subgrid ----
__global__ __launch_bounds__(BLK) void gather_kernel(const v4f* __restrict__ recs,
                                                     const unsigned* __restrict__ starts,
                                                     const float* __restrict__ grid,
                                                     float* __restrict__ out) {
    __shared__ v4f sg[SUBQ];   // 63888 B -> 2 blocks/CU

    // XCD-locality swizzle: presumed xcd = blockIdx%8 gets contiguous bucket slab
    const unsigned bb = blockIdx.x;
    const unsigned bucket = (bb & 7u) * (NBUCKETS / 8u) + (bb >> 3);
    const int bx = (int)(bucket >> 8), by = (int)((bucket >> 4) & 15u), bz = (int)(bucket & 15u);
    const int gx0 = bx * CELL, gy0 = by * CELL, gz0 = bz * CELL;

    // stage 11x11x11 voxels (48 B each = 3 float4), clamped at world edge
    for (int f = threadIdx.x; f < SUBQ; f += BLK) {
        int v = f / 3, c = f - v * 3;
        int lx = v / (SUB*SUB); int r = v - lx * (SUB*SUB);
        int ly = r / SUB;       int lz = r - ly * SUB;
        int gx = min(gx0 + lx, WDIM - 1);
        int gy = min(gy0 + ly, WDIM - 1);
        int gz = min(gz0 + lz, WDIM - 1);
        const v4f* src = reinterpret_cast<const v4f*>(
            grid + (size_t)(((gx * WDIM + gy) * WDIM + gz) * CH)) + c;
        sg[f] = *src;
    }
    __syncthreads();

    const unsigned s = starts[bucket], e = starts[bucket + 1];
    for (unsigned p = s + threadIdx.x; p < e; p += BLK) {
        v4f r = recs[p];
        const float px = r.x, py = r.y, pz = r.z;
        const unsigned idx = __float_as_uint(r.w);

        const int x0 = (int)px, y0 = (int)py, z0 = (int)pz;
        const float fx = px - (float)x0, fy = py - (float)y0, fz = pz - (float)z0;
        const float gx = 1.0f - fx, gy = 1.0f - fy, gz = 1.0f - fz;
        const int lx0 = x0 - gx0, ly0 = y0 - gy0, lz0 = z0 - gz0;
        // lx0..9; lx0+1 valid (<=10); world-edge handled by duplicated halo slot

        const float w000 = gx * gy * gz, w001 = gx * gy * fz;
        const float w010 = gx * fy * gz, w011 = gx * fy * fz;
        const float w100 = fx * gy * gz, w101 = fx * gy * fz;
        const float w110 = fx * fy * gz, w111 = fx * fy * fz;

        const int q000 = (lx0 * (SUB*SUB) + ly0 * SUB + lz0) * 3;
        const int q001 = q000 + 3;
        const int q010 = q000 + SUB * 3;
        const int q011 = q010 + 3;
        const int q100 = q000 + (SUB*SUB) * 3;
        const int q101 = q100 + 3;
        const int q110 = q100 + SUB * 3;
        const int q111 = q110 + 3;

        v4f a0 = (v4f)(0.0f), a1 = (v4f)(0.0f), a2 = (v4f)(0.0f);
        fma4(a0, w000, sg[q000+0]); fma4(a1, w000, sg[q000+1]); fma4(a2, w000, sg[q000+2]);
        fma4(a0, w001, sg[q001+0]); fma4(a1, w001, sg[q001+1]); fma4(a2, w001, sg[q001+2]);
        fma4(a0, w010, sg[q010+0]); fma4(a1, w010, sg[q010+1]); fma4(a2, w010, sg[q010+2]);
        fma4(a0, w011, sg[q011+0]); fma4(a1, w011, sg[q011+1]); fma4(a2, w011, sg[q011+2]);
        fma4(a0, w100, sg[q100+0]); fma4(a1, w100, sg[q100+1]); fma4(a2, w100, sg[q100+2]);
        fma4(a0, w101, sg[q101+0]); fma4(a1, w101, sg[q101+1]); fma4(a2, w101, sg[q101+2]);
        fma4(a0, w110, sg[q110+0]); fma4(a1, w110, sg[q110+1]); fma4(a2, w110, sg[q110+2]);
        fma4(a0, w111, sg[q111+0]); fma4(a1, w111, sg[q111+1]); fma4(a2, w111, sg[q111+2]);

        v4f* o = reinterpret_cast<v4f*>(out + (size_t)idx * CH);
        __builtin_nontemporal_store(a0, o + 0);
        __builtin_nontemporal_store(a1, o + 1);
        __builtin_nontemporal_store(a2, o + 2);
    }
}

// ---- fallback: direct kernel (round-2 version) if ws too small ----
__global__ __launch_bounds__(BLK) void trilerp_direct(const float* __restrict__ xyz,
                                                      const float* __restrict__ grid,
                                                      float* __restrict__ out, int n) {
    const int i = blockIdx.x * BLK + threadIdx.x;
    if (i >= n) return;
    float px, py, pz; int x0, y0, z0, b;
    point_prep(xyz, i, px, py, pz, x0, y0, z0, b);
    const float fx = px - (float)x0, fy = py - (float)y0, fz = pz - (float)z0;
    const float gx = 1.0f - fx, gy = 1.0f - fy, gz = 1.0f - fz;
    const int x1 = min(x0 + 1, WDIM - 1), y1 = min(y0 + 1, WDIM - 1), z1 = min(z0 + 1, WDIM - 1);
    const float w000 = gx*gy*gz, w001 = gx*gy*fz, w010 = gx*fy*gz, w011 = gx*fy*fz;
    const float w100 = fx*gy*gz, w101 = fx*gy*fz, w110 = fx*fy*gz, w111 = fx*fy*fz;
    const int b00 = ((x0*WDIM + y0)*WDIM)*CH, b01 = ((x0*WDIM + y1)*WDIM)*CH;
    const int b10 = ((x1*WDIM + y0)*WDIM)*CH, b11 = ((x1*WDIM + y1)*WDIM)*CH;
    const int oz0 = z0*CH, oz1 = z1*CH;
    v4f a0 = (v4f)(0.0f), a1 = (v4f)(0.0f), a2 = (v4f)(0.0f);
    const v4f* c;
    c = reinterpret_cast<const v4f*>(grid + b00 + oz0); fma4(a0,w000,c[0]); fma4(a1,w000,c[1]); fma4(a2,w000,c[2]);
    c = reinterpret_cast<const v4f*>(grid + b00 + oz1); fma4(a0,w001,c[0]); fma4(a1,w001,c[1]); fma4(a2,w001,c[2]);
    c = reinterpret_cast<const v4f*>(grid + b01 + oz0); fma4(a0,w010,c[0]); fma4(a1,w010,c[1]); fma4(a2,w010,c[2]);
    c = reinterpret_cast<const v4f*>(grid + b01 + oz1); fma4(a0,w011,c[0]); fma4(a1,w011,c[1]); fma4(a2,w011,c[2]);
    c = reinterpret_cast<const v4f*>(grid + b10 + oz0); fma4(a0,w100,c[0]); fma4(a1,w100,c[1]); fma4(a2,w100,c[2]);
    c = reinterpret_cast<const v4f*>(grid + b10 + oz1); fma4(a0,w101,c[0]); fma4(a1,w101,c[1]); fma4(a2,w101,c[2]);
    c = reinterpret_cast<const v4f*>(grid + b11 + oz0); fma4(a0,w110,c[0]); fma4(a1,w110,c[1]); fma4(a2,w110,c[2]);
    c = reinterpret_cast<const v4f*>(grid + b11 + oz1); fma4(a0,w111,c[0]); fma4(a1,w111,c[1]); fma4(a2,w111,c[2]);
    v4f* o = reinterpret_cast<v4f*>(out + (size_t)i * CH);
    __builtin_nontemporal_store(a0, o + 0);
    __builtin_nontemporal_store(a1, o + 1);
    __builtin_nontemporal_store(a2, o + 2);
}

extern "C" void kernel_launch(void* const* d_in, const int* in_sizes, int n_in,
                              void* d_out, int out_size, void* d_ws, size_t ws_size,
                              hipStream_t stream) {
    const float* xyz  = (const float*)d_in[0];
    const float* grid = (const float*)d_in[1];
    float* out = (float*)d_out;
    const int n = in_sizes[0] / 3;   // 2,000,000 points

    // workspace layout
    const size_t recs_bytes   = (size_t)n * 16;
    const size_t hist_off     = recs_bytes;
    const size_t starts_off   = hist_off + NBUCKETS * 4;
    const size_t cursor_off   = starts_off + (NBUCKETS + 1) * 4;
    const size_t ws_needed    = cursor_off + NBUCKETS * 4;

    if (ws_size < ws_needed) {
        trilerp_direct<<<(n + BLK - 1) / BLK, BLK, 0, stream>>>(xyz, grid, out, n);
        return;
    }

    char* ws = (char*)d_ws;
    v4f*      recs   = (v4f*)ws;
    unsigned* hist   = (unsigned*)(ws + hist_off);
    unsigned* starts = (unsigned*)(ws + starts_off);
    unsigned* cursor = (unsigned*)(ws + cursor_off);

    hipMemsetAsync(hist, 0, NBUCKETS * 4, stream);
    hist_kernel<<<256, BLK, 0, stream>>>(xyz, hist, n);
    scan_kernel<<<1, BLK, 0, stream>>>(hist, starts, cursor);
    scatter_kernel<<<1024, BLK, 0, stream>>>(xyz, cursor, recs, n);
    gather_kernel<<<NBUCKETS, BLK, 0, stream>>>(recs, starts, grid, out);
}